// Round 2
// baseline (3383.375 us; speedup 1.0000x reference)
//
#include <hip/hip_runtime.h>
#include <hip/hip_bf16.h>
#include <math.h>

#define B_ 2
#define N_ 2048
#define D_ 1024
#define H_ 16
#define DH_ 64
#define BN_ (B_*N_)
#define CHUNK_ 64
#define NCHUNK_ (N_/CHUNK_)
#define CG_ITERS_ 30

// ---------------- generic tiled GEMM: C = A @ B (all fp32) ----------------
// A: MxK row-major, B: KxN row-major, C: MxN
// 64x64 tile, 256 threads, 4x4 per thread. M%64==0, K%16==0; N guarded.
__global__ __launch_bounds__(256) void gemm_kernel(const float* __restrict__ A,
    const float* __restrict__ Bm, float* __restrict__ C, int M, int N, int K)
{
  __shared__ float As[16][65];   // [k][m]
  __shared__ float Bs[16][65];   // [k][n]
  const int tid = threadIdx.x;
  const int tile_m = blockIdx.y * 64;
  const int tile_n = blockIdx.x * 64;
  const int tr = tid >> 4;       // 0..15
  const int tc = tid & 15;       // 0..15
  float acc[4][4];
#pragma unroll
  for (int i=0;i<4;i++)
#pragma unroll
    for (int j=0;j<4;j++) acc[i][j]=0.f;

  for (int k0=0;k0<K;k0+=16) {
#pragma unroll
    for (int i=0;i<4;i++){
      int flat = i*256+tid;
      int ar = flat>>4, ak = flat&15;
      As[ak][ar] = A[(size_t)(tile_m+ar)*K + k0+ak];
      int kr = flat>>6, cc = flat&63;
      int col = tile_n + cc;
      Bs[kr][cc] = (col < N) ? Bm[(size_t)(k0+kr)*N + col] : 0.f;
    }
    __syncthreads();
#pragma unroll
    for (int kk=0;kk<16;kk++){
      float a[4], b[4];
#pragma unroll
      for (int u=0;u<4;u++){ a[u]=As[kk][tr*4+u]; b[u]=Bs[kk][tc*4+u]; }
#pragma unroll
      for (int i=0;i<4;i++)
#pragma unroll
        for (int j=0;j<4;j++) acc[i][j] += a[i]*b[j];
    }
    __syncthreads();
  }
#pragma unroll
  for (int i=0;i<4;i++){
#pragma unroll
    for (int j=0;j<4;j++){
      int col = tile_n + tc*4+j;
      if (col < N) C[(size_t)(tile_m + tr*4+i)*N + col] = acc[i][j];
    }
  }
}

// ---------------- lamb = softplus(lamb_params) + 0.25 ----------------
__global__ void k_lamb(const float* __restrict__ lp, float* __restrict__ lamb){
  int i = blockIdx.x*256 + threadIdx.x;
  if (i < D_){
    float z = lp[i];
    float sp = fmaxf(z, 0.f) + log1pf(expf(-fabsf(z)));
    lamb[i] = sp + 0.25f;
  }
}

// ---------------- per-head l2norm of q,k (in place) ----------------
__global__ __launch_bounds__(256) void k_l2norm(float* __restrict__ q, float* __restrict__ k){
  int bn = blockIdx.x;
  int wave = threadIdx.x >> 6, lane = threadIdx.x & 63;
#pragma unroll
  for (int e=0; e<4; e++){
    int h = e*4 + wave;
    size_t idx = (size_t)bn*D_ + h*DH_ + lane;
    float qv = q[idx], kv = k[idx];
    float sq = qv*qv, sk = kv*kv;
#pragma unroll
    for (int off=32; off>=1; off>>=1){ sq += __shfl_xor(sq, off); sk += __shfl_xor(sk, off); }
    q[idx] = qv * rsqrtf(sq + 1e-6f);
    k[idx] = kv * rsqrtf(sk + 1e-6f);
  }
}

// ---------------- log_f, beta, cumulative F per (b,h) ----------------
__global__ __launch_bounds__(256) void k_scan(const float* __restrict__ flogit,
    const float* __restrict__ blogit, const float* __restrict__ delta,
    float* __restrict__ logf, float* __restrict__ F, float* __restrict__ beta)
{
  int bh = blockIdx.x; int b = bh >> 4; int h = bh & 15;
  int tid = threadIdx.x;
  __shared__ float tot[256];
  float dl = delta[h];
  float loc[8];
  float run = 0.f;
#pragma unroll
  for (int u=0;u<8;u++){
    int t = tid*8+u;
    float z = flogit[(size_t)(b*N_+t)*H_ + h] + dl;
    float lf = fminf(z,0.f) - log1pf(expf(-fabsf(z)));
    logf[(size_t)bh*N_ + t] = lf;
    float zb = blogit[(size_t)(b*N_+t)*H_ + h];
    beta[(size_t)bh*N_ + t] = 1.f/(1.f+expf(-zb));
    run += lf; loc[u] = run;
  }
  tot[tid] = run;
  __syncthreads();
  for (int off=1; off<256; off<<=1){
    float add = (tid>=off)? tot[tid-off] : 0.f;
    __syncthreads();
    tot[tid] += add;
    __syncthreads();
  }
  float offset = (tid>0)? tot[tid-1] : 0.f;
#pragma unroll
  for (int u=0;u<8;u++){
    F[(size_t)bh*N_ + tid*8+u] = offset + loc[u];
  }
}

// ---------------- chunk-local weighted Gram sums (at chunk END) ----------------
// L_kk[i][j] = sum_s exp(F_end - F_s) * beta_s * k_s[i] * k_s[j]   (s in chunk)
// L_kv[i][j] = sum_s exp(F_end - F_s) * beta_s * k_s[i] * v_s[j]
__global__ __launch_bounds__(256) void k_chunk(const float* __restrict__ kg,
    const float* __restrict__ vg, const float* __restrict__ F,
    const float* __restrict__ beta, float* __restrict__ Skk, float* __restrict__ Skv)
{
  int blk = blockIdx.x;
  int c = blk & (NCHUNK_-1); int bh = blk >> 5; int b = bh >> 4; int h = bh & 15;
  int t0 = c*CHUNK_;
  int tid = threadIdx.x;
  __shared__ float Ks[64][65];
  __shared__ float Vs[64][65];
  __shared__ float w[64];
#pragma unroll 4
  for (int i=0;i<16;i++){
    int flat=i*256+tid; int s=flat>>6; int j=flat&63;
    size_t g = (size_t)(b*N_+t0+s)*D_ + h*DH_ + j;
    Ks[s][j] = kg[g]; Vs[s][j] = vg[g];
  }
  if (tid < 64){
    float Fe = F[(size_t)bh*N_ + t0 + 63];
    w[tid] = expf(Fe - F[(size_t)bh*N_ + t0 + tid]) * beta[(size_t)bh*N_ + t0 + tid];
  }
  __syncthreads();
  int i0 = (tid>>4)<<2, j0 = (tid&15)<<2;
  float akk[4][4], akv[4][4];
#pragma unroll
  for (int a=0;a<4;a++)
#pragma unroll
    for (int bb=0;bb<4;bb++){ akk[a][bb]=0.f; akv[a][bb]=0.f; }
  for (int s=0;s<64;s++){
    float ws_ = w[s];
    float ka[4], kb[4], vb[4];
#pragma unroll
    for (int a=0;a<4;a++){ ka[a] = ws_*Ks[s][i0+a]; kb[a] = Ks[s][j0+a]; vb[a] = Vs[s][j0+a]; }
#pragma unroll
    for (int a=0;a<4;a++)
#pragma unroll
      for (int bb=0;bb<4;bb++){
        akk[a][bb] += ka[a]*kb[bb];
        akv[a][bb] += ka[a]*vb[bb];
      }
  }
  size_t base = ((size_t)bh*NCHUNK_ + c)*4096;
#pragma unroll
  for (int a=0;a<4;a++)
#pragma unroll
    for (int bb=0;bb<4;bb++){
      Skk[base + (size_t)(i0+a)*64 + j0+bb] = akk[a][bb];
      Skv[base + (size_t)(i0+a)*64 + j0+bb] = akv[a][bb];
    }
}

// ---------------- sequential chunk combine: local sums -> chunk-START states (in place) ----------------
__global__ __launch_bounds__(256) void k_combine(float* __restrict__ Skk,
    float* __restrict__ Skv, const float* __restrict__ F)
{
  int bh = blockIdx.x; int tid = threadIdx.x;
  float Rkk[16], Rkv[16];
#pragma unroll
  for (int u=0;u<16;u++){ Rkk[u]=0.f; Rkv[u]=0.f; }
  float Fprev = 0.f;
  for (int c=0;c<NCHUNK_;c++){
    float Fe = F[(size_t)bh*N_ + c*CHUNK_ + 63];
    float E = expf(Fe - Fprev);
    Fprev = Fe;
    size_t base = ((size_t)bh*NCHUNK_ + c)*4096;
#pragma unroll
    for (int u=0;u<16;u++){
      size_t e = base + (size_t)u*256 + tid;
      float lkk = Skk[e], lkv = Skv[e];
      Skk[e] = Rkk[u]; Skv[e] = Rkv[u];
      Rkk[u] = E*Rkk[u] + lkk;
      Rkv[u] = E*Rkv[u] + lkv;
    }
  }
}

// ---------------- pass B: per (b,h,chunk) replay chunk; CG(30) per t; o_t = x^T Z ----------------
__global__ __launch_bounds__(256) void k_passB(const float* __restrict__ qg,
    const float* __restrict__ kg, const float* __restrict__ vg,
    const float* __restrict__ logf, const float* __restrict__ beta,
    const float* __restrict__ lamb,
    const float* __restrict__ Skk, const float* __restrict__ Skv,
    float* __restrict__ o)
{
  int blk = blockIdx.x;
  int c = blk & (NCHUNK_-1); int bh = blk >> 5; int b = bh >> 4; int h = bh & 15;
  int t0 = c*CHUNK_;
  int tid = threadIdx.x;
  __shared__ float Ss[64][65];
  __shared__ float Zs[64][65];
  __shared__ float kvec[64], vvec[64], pv[64], xl[64];
  __shared__ float part[4][64];
  size_t base = ((size_t)bh*NCHUNK_ + c)*4096;
#pragma unroll 4
  for (int i=0;i<16;i++){
    int flat = i*256+tid; int rr = flat>>6; int cc = flat&63;
    Ss[rr][cc] = Skk[base+flat];
    Zs[rr][cc] = Skv[base+flat];
  }
  const int lane = tid & 63;
  const int g = tid >> 6;
  const float lamb_l = lamb[h*DH_ + lane];
  __syncthreads();

  for (int t=0; t<CHUNK_; t++){
    int tt = t0 + t;
    float fexp = expf(logf[(size_t)bh*N_ + tt]);
    float bet  = beta[(size_t)bh*N_ + tt];
    size_t gidx = (size_t)(b*N_+tt)*D_ + h*DH_ + lane;
    if (tid < 64){
      kvec[lane] = kg[gidx];
      vvec[lane] = vg[gidx];
    }
    __syncthreads();                       // A: kvec/vvec visible
    // rank-1 state update (exact reference recurrence)
#pragma unroll 4
    for (int i=0;i<16;i++){
      int flat = i*256+tid; int rr = flat>>6; int cc = flat&63;
      float bk = bet * kvec[rr];
      Ss[rr][cc] = fexp*Ss[rr][cc] + bk*kvec[cc];
      Zs[rr][cc] = fexp*Zs[rr][cc] + bk*vvec[cc];
    }
    __syncthreads();                       // B: state updated before matvecs
    // ---- CG: vectors owned by wave0 (regs), p broadcast via LDS, matvec by all 4 waves ----
    float x_r = 0.f, r_r = 0.f, rs = 0.f;
    if (tid < 64){
      float qv = qg[gidx];
      r_r = qv;
      pv[lane] = qv;
      float s = qv*qv;
#pragma unroll
      for (int off=32; off>=1; off>>=1) s += __shfl_xor(s, off);
      rs = s;
    }
    for (int it=0; it<CG_ITERS_; it++){
      __syncthreads();                     // C: pv ready
      float accm = 0.f;
#pragma unroll
      for (int jj=0;jj<16;jj++) accm += Ss[lane][g*16+jj] * pv[g*16+jj];
      part[g][lane] = accm;
      __syncthreads();                     // D: partials ready
      if (tid < 64){
        float Ap = part[0][lane]+part[1][lane]+part[2][lane]+part[3][lane] + lamb_l*pv[lane];
        float pd = pv[lane]*Ap;
#pragma unroll
        for (int off=32; off>=1; off>>=1) pd += __shfl_xor(pd, off);
        float alpha = rs / (pd + 1e-12f);
        float p_l = pv[lane];
        x_r += alpha * p_l;
        r_r -= alpha * Ap;
        float rn = r_r*r_r;
#pragma unroll
        for (int off=32; off>=1; off>>=1) rn += __shfl_xor(rn, off);
        pv[lane] = r_r + (rn/(rs+1e-12f)) * p_l;
        rs = rn;
      }
    }
    if (tid < 64) xl[lane] = x_r;
    __syncthreads();                       // E: xl ready
    float accm = 0.f;
#pragma unroll
    for (int ii=0;ii<16;ii++) accm += Zs[g*16+ii][lane] * xl[g*16+ii];
    part[g][lane] = accm;
    __syncthreads();                       // F: output partials ready
    if (tid < 64){
      o[gidx] = part[0][lane]+part[1][lane]+part[2][lane]+part[3][lane];
    }
    __syncthreads();                       // G: done with part/xl before next t
  }
}

// ---------------- gate + grouped RMSNorm (in place on o) ----------------
__global__ __launch_bounds__(256) void k_gate(float* __restrict__ o,
    const float* __restrict__ g1, const float* __restrict__ gw2,
    const float* __restrict__ nw)
{
  int bn = blockIdx.x;
  int tid = threadIdx.x;
  __shared__ float g1s[64];
  if (tid < 64) g1s[tid] = g1[(size_t)bn*DH_ + tid];
  __syncthreads();
  int wave = tid>>6, lane = tid&63;
#pragma unroll
  for (int e=0;e<4;e++){
    int h = e*4 + wave;
    int col = h*DH_ + lane;
    float zl = 0.f;
    for (int cc=0; cc<64; cc++){
      zl += g1s[cc] * gw2[(size_t)cc*D_ + col];
    }
    float gate = 1.f/(1.f+expf(-zl));
    size_t idx = (size_t)bn*D_ + col;
    float og = o[idx] * gate;
    float ss = og*og;
#pragma unroll
    for (int off=32; off>=1; off>>=1) ss += __shfl_xor(ss, off);
    og *= rsqrtf(ss*(1.f/64.f) + 1e-5f);
    og *= nw[col];
    o[idx] = og;
  }
}

// ---------------- workspace layout (floats) ----------------
#define OFF_Q      ((size_t)0)
#define OFF_K      ((size_t)4194304)
#define OFF_V      ((size_t)8388608)
#define OFF_O      ((size_t)12582912)
#define OFF_SKK    ((size_t)16777216)
#define OFF_SKV    ((size_t)20971520)
#define OFF_G1     ((size_t)25165824)
#define OFF_FLOG   ((size_t)25427968)
#define OFF_BLOG   ((size_t)25493504)
#define OFF_LOGF   ((size_t)25559040)
#define OFF_F      ((size_t)25624576)
#define OFF_BETA   ((size_t)25690112)
#define OFF_LAMB   ((size_t)25755648)
// total 25,756,672 floats = 103.0 MB

extern "C" void kernel_launch(void* const* d_in, const int* in_sizes, int n_in,
                              void* d_out, int out_size, void* d_ws, size_t ws_size,
                              hipStream_t stream)
{
  const float* x     = (const float*)d_in[0];
  const float* Wq    = (const float*)d_in[1];
  const float* Wk    = (const float*)d_in[2];
  const float* Wv    = (const float*)d_in[3];
  const float* Wf    = (const float*)d_in[4];
  const float* Wbet  = (const float*)d_in[5];
  const float* Wo    = (const float*)d_in[6];
  const float* delta = (const float*)d_in[7];
  const float* lambp = (const float*)d_in[8];
  const float* nw    = (const float*)d_in[9];
  const float* gw1   = (const float*)d_in[10];
  const float* gw2   = (const float*)d_in[11];

  float* ws = (float*)d_ws;
  float* q      = ws + OFF_Q;
  float* kbuf   = ws + OFF_K;
  float* vbuf   = ws + OFF_V;
  float* obuf   = ws + OFF_O;
  float* Skk    = ws + OFF_SKK;
  float* Skv    = ws + OFF_SKV;
  float* g1     = ws + OFF_G1;
  float* flogit = ws + OFF_FLOG;
  float* blogit = ws + OFF_BLOG;
  float* logf   = ws + OFF_LOGF;
  float* F      = ws + OFF_F;
  float* beta   = ws + OFF_BETA;
  float* lamb   = ws + OFF_LAMB;

  dim3 blk(256,1,1);
  // projections
  gemm_kernel<<<dim3(16,64), blk, 0, stream>>>(x, Wq,   q,      BN_, D_,  D_);
  gemm_kernel<<<dim3(16,64), blk, 0, stream>>>(x, Wk,   kbuf,   BN_, D_,  D_);
  gemm_kernel<<<dim3(16,64), blk, 0, stream>>>(x, Wv,   vbuf,   BN_, D_,  D_);
  gemm_kernel<<<dim3(1,64),  blk, 0, stream>>>(x, Wf,   flogit, BN_, H_,  D_);
  gemm_kernel<<<dim3(1,64),  blk, 0, stream>>>(x, Wbet, blogit, BN_, H_,  D_);
  gemm_kernel<<<dim3(1,64),  blk, 0, stream>>>(x, gw1,  g1,     BN_, DH_, D_);
  // small prep
  k_lamb<<<dim3(4), blk, 0, stream>>>(lambp, lamb);
  k_l2norm<<<dim3(BN_), blk, 0, stream>>>(q, kbuf);
  k_scan<<<dim3(B_*H_), blk, 0, stream>>>(flogit, blogit, delta, logf, F, beta);
  // chunked linear scan of Gram states
  k_chunk<<<dim3(B_*H_*NCHUNK_), blk, 0, stream>>>(kbuf, vbuf, F, beta, Skk, Skv);
  k_combine<<<dim3(B_*H_), blk, 0, stream>>>(Skk, Skv, F);
  // heavy pass: per-chunk replay + CG solves + outputs
  k_passB<<<dim3(B_*H_*NCHUNK_), blk, 0, stream>>>(q, kbuf, vbuf, logf, beta, lamb, Skk, Skv, obuf);
  // epilogue: gate + grouped RMSNorm, then output projection
  k_gate<<<dim3(BN_), blk, 0, stream>>>(obuf, g1, gw2, nw);
  gemm_kernel<<<dim3(16,64), blk, 0, stream>>>(obuf, Wo, (float*)d_out, BN_, D_, D_);
}

// Round 3
// 2778.495 us; speedup vs baseline: 1.2177x; 1.2177x over previous
//
#include <hip/hip_runtime.h>
#include <hip/hip_bf16.h>
#include <math.h>

#define B_ 2
#define N_ 2048
#define D_ 1024
#define H_ 16
#define DH_ 64
#define BN_ (B_*N_)
#define CHUNK_ 64
#define NCHUNK_ (N_/CHUNK_)
#define CG_ITERS_ 30

// ---------------- generic tiled GEMM: C = A @ B (all fp32) ----------------
__global__ __launch_bounds__(256) void gemm_kernel(const float* __restrict__ A,
    const float* __restrict__ Bm, float* __restrict__ C, int M, int N, int K)
{
  __shared__ float As[16][65];   // [k][m]
  __shared__ float Bs[16][65];   // [k][n]
  const int tid = threadIdx.x;
  const int tile_m = blockIdx.y * 64;
  const int tile_n = blockIdx.x * 64;
  const int tr = tid >> 4;
  const int tc = tid & 15;
  float acc[4][4];
#pragma unroll
  for (int i=0;i<4;i++)
#pragma unroll
    for (int j=0;j<4;j++) acc[i][j]=0.f;

  for (int k0=0;k0<K;k0+=16) {
#pragma unroll
    for (int i=0;i<4;i++){
      int flat = i*256+tid;
      int ar = flat>>4, ak = flat&15;
      As[ak][ar] = A[(size_t)(tile_m+ar)*K + k0+ak];
      int kr = flat>>6, cc = flat&63;
      int col = tile_n + cc;
      Bs[kr][cc] = (col < N) ? Bm[(size_t)(k0+kr)*N + col] : 0.f;
    }
    __syncthreads();
#pragma unroll
    for (int kk=0;kk<16;kk++){
      float a[4], b[4];
#pragma unroll
      for (int u=0;u<4;u++){ a[u]=As[kk][tr*4+u]; b[u]=Bs[kk][tc*4+u]; }
#pragma unroll
      for (int i=0;i<4;i++)
#pragma unroll
        for (int j=0;j<4;j++) acc[i][j] += a[i]*b[j];
    }
    __syncthreads();
  }
#pragma unroll
  for (int i=0;i<4;i++){
#pragma unroll
    for (int j=0;j<4;j++){
      int col = tile_n + tc*4+j;
      if (col < N) C[(size_t)(tile_m + tr*4+i)*N + col] = acc[i][j];
    }
  }
}

// ---------------- lamb = softplus(lamb_params) + 0.25 ----------------
__global__ void k_lamb(const float* __restrict__ lp, float* __restrict__ lamb){
  int i = blockIdx.x*256 + threadIdx.x;
  if (i < D_){
    float z = lp[i];
    float sp = fmaxf(z, 0.f) + log1pf(expf(-fabsf(z)));
    lamb[i] = sp + 0.25f;
  }
}

// ---------------- per-head l2norm of q,k (in place) ----------------
__global__ __launch_bounds__(256) void k_l2norm(float* __restrict__ q, float* __restrict__ k){
  int bn = blockIdx.x;
  int wave = threadIdx.x >> 6, lane = threadIdx.x & 63;
#pragma unroll
  for (int e=0; e<4; e++){
    int h = e*4 + wave;
    size_t idx = (size_t)bn*D_ + h*DH_ + lane;
    float qv = q[idx], kv = k[idx];
    float sq = qv*qv, sk = kv*kv;
#pragma unroll
    for (int off=32; off>=1; off>>=1){ sq += __shfl_xor(sq, off); sk += __shfl_xor(sk, off); }
    q[idx] = qv * rsqrtf(sq + 1e-6f);
    k[idx] = kv * rsqrtf(sk + 1e-6f);
  }
}

// ---------------- log_f, beta, cumulative F per (b,h) ----------------
__global__ __launch_bounds__(256) void k_scan(const float* __restrict__ flogit,
    const float* __restrict__ blogit, const float* __restrict__ delta,
    float* __restrict__ logf, float* __restrict__ F, float* __restrict__ beta)
{
  int bh = blockIdx.x; int b = bh >> 4; int h = bh & 15;
  int tid = threadIdx.x;
  __shared__ float tot[256];
  float dl = delta[h];
  float loc[8];
  float run = 0.f;
#pragma unroll
  for (int u=0;u<8;u++){
    int t = tid*8+u;
    float z = flogit[(size_t)(b*N_+t)*H_ + h] + dl;
    float lf = fminf(z,0.f) - log1pf(expf(-fabsf(z)));
    logf[(size_t)bh*N_ + t] = lf;
    float zb = blogit[(size_t)(b*N_+t)*H_ + h];
    beta[(size_t)bh*N_ + t] = 1.f/(1.f+expf(-zb));
    run += lf; loc[u] = run;
  }
  tot[tid] = run;
  __syncthreads();
  for (int off=1; off<256; off<<=1){
    float add = (tid>=off)? tot[tid-off] : 0.f;
    __syncthreads();
    tot[tid] += add;
    __syncthreads();
  }
  float offset = (tid>0)? tot[tid-1] : 0.f;
#pragma unroll
  for (int u=0;u<8;u++){
    F[(size_t)bh*N_ + tid*8+u] = offset + loc[u];
  }
}

// ---------------- chunk-local weighted Gram sums (at chunk END) ----------------
__global__ __launch_bounds__(256) void k_chunk(const float* __restrict__ kg,
    const float* __restrict__ vg, const float* __restrict__ F,
    const float* __restrict__ beta, float* __restrict__ Skk, float* __restrict__ Skv)
{
  int blk = blockIdx.x;
  int c = blk & (NCHUNK_-1); int bh = blk >> 5; int b = bh >> 4; int h = bh & 15;
  int t0 = c*CHUNK_;
  int tid = threadIdx.x;
  __shared__ float Ks[64][65];
  __shared__ float Vs[64][65];
  __shared__ float w[64];
#pragma unroll 4
  for (int i=0;i<16;i++){
    int flat=i*256+tid; int s=flat>>6; int j=flat&63;
    size_t g = (size_t)(b*N_+t0+s)*D_ + h*DH_ + j;
    Ks[s][j] = kg[g]; Vs[s][j] = vg[g];
  }
  if (tid < 64){
    float Fe = F[(size_t)bh*N_ + t0 + 63];
    w[tid] = expf(Fe - F[(size_t)bh*N_ + t0 + tid]) * beta[(size_t)bh*N_ + t0 + tid];
  }
  __syncthreads();
  int i0 = (tid>>4)<<2, j0 = (tid&15)<<2;
  float akk[4][4], akv[4][4];
#pragma unroll
  for (int a=0;a<4;a++)
#pragma unroll
    for (int bb=0;bb<4;bb++){ akk[a][bb]=0.f; akv[a][bb]=0.f; }
  for (int s=0;s<64;s++){
    float ws_ = w[s];
    float ka[4], kb[4], vb[4];
#pragma unroll
    for (int a=0;a<4;a++){ ka[a] = ws_*Ks[s][i0+a]; kb[a] = Ks[s][j0+a]; vb[a] = Vs[s][j0+a]; }
#pragma unroll
    for (int a=0;a<4;a++)
#pragma unroll
      for (int bb=0;bb<4;bb++){
        akk[a][bb] += ka[a]*kb[bb];
        akv[a][bb] += ka[a]*vb[bb];
      }
  }
  size_t base = ((size_t)bh*NCHUNK_ + c)*4096;
#pragma unroll
  for (int a=0;a<4;a++)
#pragma unroll
    for (int bb=0;bb<4;bb++){
      Skk[base + (size_t)(i0+a)*64 + j0+bb] = akk[a][bb];
      Skv[base + (size_t)(i0+a)*64 + j0+bb] = akv[a][bb];
    }
}

// ---------------- sequential chunk combine: local sums -> chunk-START states ----------------
__global__ __launch_bounds__(256) void k_combine(float* __restrict__ Skk,
    float* __restrict__ Skv, const float* __restrict__ F)
{
  int bh = blockIdx.x; int tid = threadIdx.x;
  float Rkk[16], Rkv[16];
#pragma unroll
  for (int u=0;u<16;u++){ Rkk[u]=0.f; Rkv[u]=0.f; }
  float Fprev = 0.f;
  for (int c=0;c<NCHUNK_;c++){
    float Fe = F[(size_t)bh*N_ + c*CHUNK_ + 63];
    float E = expf(Fe - Fprev);
    Fprev = Fe;
    size_t base = ((size_t)bh*NCHUNK_ + c)*4096;
#pragma unroll
    for (int u=0;u<16;u++){
      size_t e = base + (size_t)u*256 + tid;
      float lkk = Skk[e], lkv = Skv[e];
      Skk[e] = Rkk[u]; Skv[e] = Rkv[u];
      Rkk[u] = E*Rkk[u] + lkk;
      Rkv[u] = E*Rkv[u] + lkv;
    }
  }
}

// ---------------- wave-resident CG kernel ----------------
// One 64-lane wave per (b,h,half-chunk of 32 steps). State S (64x64, symmetric)
// in registers: lane i holds row i (== col i). Z: lane j holds column j.
// CG vectors element-per-lane; p broadcast via 64-float LDS (float4 broadcast reads).
// Odd halves replay 32 state-only rank-1 updates from the stored chunk-start state.
__device__ __forceinline__ float wred(float v){
#pragma unroll
  for (int off=32; off>=1; off>>=1) v += __shfl_xor(v, off);
  return v;
}

__global__ __launch_bounds__(64, 2) void k_cgwave(
    const float* __restrict__ qg, const float* __restrict__ kg,
    const float* __restrict__ vg, const float* __restrict__ logf,
    const float* __restrict__ beta, const float* __restrict__ lamb,
    const float* __restrict__ Skk, const float* __restrict__ Skv,
    float* __restrict__ o)
{
  const int blk = blockIdx.x;           // 2048 = 32 bh * 32 cc * 2 halves
  const int bh   = blk >> 6;
  const int sub  = blk & 63;
  const int cc   = sub >> 1;
  const int half = sub & 1;
  const int b = bh >> 4, h = bh & 15;
  const int lane = threadIdx.x;

  __shared__ __align__(16) float pv[64];
  __shared__ __align__(16) float kv[64];
  __shared__ __align__(16) float vv[64];
  __shared__ __align__(16) float xv[64];

  float S[64], Z[64];
  const size_t base = ((size_t)bh*NCHUNK_ + cc)*4096;
  // S symmetric: row(lane) == col(lane): coalesced column load for both
#pragma unroll
  for (int j=0;j<64;j++){
    S[j] = Skk[base + (size_t)j*64 + lane];
    Z[j] = Skv[base + (size_t)j*64 + lane];
  }
  const float laml = lamb[h*DH_ + lane];

  const int tstart  = cc*CHUNK_;
  const int cgstart = tstart + half*32;

  // ---- replay phase (state-only) for odd halves ----
  for (int tt=tstart; tt<cgstart; tt++){
    float fexp = expf(logf[(size_t)bh*N_ + tt]);
    float bet  = beta[(size_t)bh*N_ + tt];
    size_t gidx = (size_t)(b*N_+tt)*D_ + h*DH_ + lane;
    float kl = kg[gidx], vl = vg[gidx];
    kv[lane] = kl; vv[lane] = vl;
    __syncthreads();
    float bk = bet*kl;        // S row-lane update coeff
    float bvv = bet*vl;       // Z col-lane update coeff
#pragma unroll
    for (int u=0;u<16;u++){
      float4 k4 = *(const float4*)&kv[4*u];
      S[4*u+0] = fexp*S[4*u+0] + bk*k4.x;
      S[4*u+1] = fexp*S[4*u+1] + bk*k4.y;
      S[4*u+2] = fexp*S[4*u+2] + bk*k4.z;
      S[4*u+3] = fexp*S[4*u+3] + bk*k4.w;
      Z[4*u+0] = fexp*Z[4*u+0] + k4.x*bvv;
      Z[4*u+1] = fexp*Z[4*u+1] + k4.y*bvv;
      Z[4*u+2] = fexp*Z[4*u+2] + k4.z*bvv;
      Z[4*u+3] = fexp*Z[4*u+3] + k4.w*bvv;
    }
    __syncthreads();
  }

  // ---- CG phase: 32 timesteps ----
  for (int tt=cgstart; tt<cgstart+32; tt++){
    float fexp = expf(logf[(size_t)bh*N_ + tt]);
    float bet  = beta[(size_t)bh*N_ + tt];
    size_t gidx = (size_t)(b*N_+tt)*D_ + h*DH_ + lane;
    float kl = kg[gidx], vl = vg[gidx], ql = qg[gidx];
    kv[lane] = kl; vv[lane] = vl; pv[lane] = ql;
    __syncthreads();
    // state rank-1 update (exact reference recurrence)
    float bk = bet*kl;
    float bvv = bet*vl;
#pragma unroll
    for (int u=0;u<16;u++){
      float4 k4 = *(const float4*)&kv[4*u];
      S[4*u+0] = fexp*S[4*u+0] + bk*k4.x;
      S[4*u+1] = fexp*S[4*u+1] + bk*k4.y;
      S[4*u+2] = fexp*S[4*u+2] + bk*k4.z;
      S[4*u+3] = fexp*S[4*u+3] + bk*k4.w;
      Z[4*u+0] = fexp*Z[4*u+0] + k4.x*bvv;
      Z[4*u+1] = fexp*Z[4*u+1] + k4.y*bvv;
      Z[4*u+2] = fexp*Z[4*u+2] + k4.z*bvv;
      Z[4*u+3] = fexp*Z[4*u+3] + k4.w*bvv;
    }
    // ---- CG: 30 iters, all cross-lane via shuffles; p broadcast via LDS ----
    float p_l = ql, r_l = ql, x_l = 0.f;
    float rs = wred(ql*ql);
#pragma unroll 1
    for (int it=0; it<CG_ITERS_; it++){
      // matvec Ap[lane] = S_row(lane) . p   (broadcast float4 reads, conflict-free)
      float a0=0.f, a1=0.f, a2=0.f, a3=0.f;
#pragma unroll
      for (int u=0;u<16;u++){
        float4 p4 = *(const float4*)&pv[4*u];
        a0 += S[4*u+0]*p4.x;
        a1 += S[4*u+1]*p4.y;
        a2 += S[4*u+2]*p4.z;
        a3 += S[4*u+3]*p4.w;
      }
      float ap = (a0+a1)+(a2+a3) + laml*p_l;
      float pAp = wred(p_l*ap);
      float alpha = rs / (pAp + 1e-12f);
      x_l += alpha * p_l;
      r_l -= alpha * ap;
      float rn = wred(r_l*r_l);
      p_l = r_l + (rn/(rs+1e-12f)) * p_l;
      rs = rn;
      __syncthreads();
      pv[lane] = p_l;
      __syncthreads();
    }
    // output: o[j] = sum_i x[i] * Z_col_j[i]
    xv[lane] = x_l;
    __syncthreads();
    float o0=0.f, o1=0.f, o2=0.f, o3=0.f;
#pragma unroll
    for (int u=0;u<16;u++){
      float4 x4 = *(const float4*)&xv[4*u];
      o0 += Z[4*u+0]*x4.x;
      o1 += Z[4*u+1]*x4.y;
      o2 += Z[4*u+2]*x4.z;
      o3 += Z[4*u+3]*x4.w;
    }
    o[gidx] = (o0+o1)+(o2+o3);
    __syncthreads();
  }
}

// ---------------- gate + grouped RMSNorm (in place on o) ----------------
__global__ __launch_bounds__(256) void k_gate(float* __restrict__ o,
    const float* __restrict__ g1, const float* __restrict__ gw2,
    const float* __restrict__ nw)
{
  int bn = blockIdx.x;
  int tid = threadIdx.x;
  __shared__ float g1s[64];
  if (tid < 64) g1s[tid] = g1[(size_t)bn*DH_ + tid];
  __syncthreads();
  int wave = tid>>6, lane = tid&63;
#pragma unroll
  for (int e=0;e<4;e++){
    int h = e*4 + wave;
    int col = h*DH_ + lane;
    float zl = 0.f;
    for (int cc=0; cc<64; cc++){
      zl += g1s[cc] * gw2[(size_t)cc*D_ + col];
    }
    float gate = 1.f/(1.f+expf(-zl));
    size_t idx = (size_t)bn*D_ + col;
    float og = o[idx] * gate;
    float ss = og*og;
#pragma unroll
    for (int off=32; off>=1; off>>=1) ss += __shfl_xor(ss, off);
    og *= rsqrtf(ss*(1.f/64.f) + 1e-5f);
    og *= nw[col];
    o[idx] = og;
  }
}

// ---------------- workspace layout (floats) ----------------
#define OFF_Q      ((size_t)0)
#define OFF_K      ((size_t)4194304)
#define OFF_V      ((size_t)8388608)
#define OFF_O      ((size_t)12582912)
#define OFF_SKK    ((size_t)16777216)
#define OFF_SKV    ((size_t)20971520)
#define OFF_G1     ((size_t)25165824)
#define OFF_FLOG   ((size_t)25427968)
#define OFF_BLOG   ((size_t)25493504)
#define OFF_LOGF   ((size_t)25559040)
#define OFF_F      ((size_t)25624576)
#define OFF_BETA   ((size_t)25690112)
#define OFF_LAMB   ((size_t)25755648)
// total 25,756,672 floats = 103.0 MB

extern "C" void kernel_launch(void* const* d_in, const int* in_sizes, int n_in,
                              void* d_out, int out_size, void* d_ws, size_t ws_size,
                              hipStream_t stream)
{
  const float* x     = (const float*)d_in[0];
  const float* Wq    = (const float*)d_in[1];
  const float* Wk    = (const float*)d_in[2];
  const float* Wv    = (const float*)d_in[3];
  const float* Wf    = (const float*)d_in[4];
  const float* Wbet  = (const float*)d_in[5];
  const float* Wo    = (const float*)d_in[6];
  const float* delta = (const float*)d_in[7];
  const float* lambp = (const float*)d_in[8];
  const float* nw    = (const float*)d_in[9];
  const float* gw1   = (const float*)d_in[10];
  const float* gw2   = (const float*)d_in[11];

  float* ws = (float*)d_ws;
  float* q      = ws + OFF_Q;
  float* kbuf   = ws + OFF_K;
  float* vbuf   = ws + OFF_V;
  float* obuf   = ws + OFF_O;
  float* Skk    = ws + OFF_SKK;
  float* Skv    = ws + OFF_SKV;
  float* g1     = ws + OFF_G1;
  float* flogit = ws + OFF_FLOG;
  float* blogit = ws + OFF_BLOG;
  float* logf   = ws + OFF_LOGF;
  float* F      = ws + OFF_F;
  float* beta   = ws + OFF_BETA;
  float* lamb   = ws + OFF_LAMB;

  dim3 blk(256,1,1);
  // projections
  gemm_kernel<<<dim3(16,64), blk, 0, stream>>>(x, Wq,   q,      BN_, D_,  D_);
  gemm_kernel<<<dim3(16,64), blk, 0, stream>>>(x, Wk,   kbuf,   BN_, D_,  D_);
  gemm_kernel<<<dim3(16,64), blk, 0, stream>>>(x, Wv,   vbuf,   BN_, D_,  D_);
  gemm_kernel<<<dim3(1,64),  blk, 0, stream>>>(x, Wf,   flogit, BN_, H_,  D_);
  gemm_kernel<<<dim3(1,64),  blk, 0, stream>>>(x, Wbet, blogit, BN_, H_,  D_);
  gemm_kernel<<<dim3(1,64),  blk, 0, stream>>>(x, gw1,  g1,     BN_, DH_, D_);
  // small prep
  k_lamb<<<dim3(4), blk, 0, stream>>>(lambp, lamb);
  k_l2norm<<<dim3(BN_), blk, 0, stream>>>(q, kbuf);
  k_scan<<<dim3(B_*H_), blk, 0, stream>>>(flogit, blogit, delta, logf, F, beta);
  // chunked linear scan of Gram states
  k_chunk<<<dim3(B_*H_*NCHUNK_), blk, 0, stream>>>(kbuf, vbuf, F, beta, Skk, Skv);
  k_combine<<<dim3(B_*H_), blk, 0, stream>>>(Skk, Skv, F);
  // heavy pass: wave-resident replay + CG + outputs (one wave per 32-step half-chunk)
  k_cgwave<<<dim3(B_*H_*NCHUNK_*2), dim3(64,1,1), 0, stream>>>(
      q, kbuf, vbuf, logf, beta, lamb, Skk, Skv, obuf);
  // epilogue: gate + grouped RMSNorm, then output projection
  k_gate<<<dim3(BN_), blk, 0, stream>>>(obuf, g1, gw2, nw);
  gemm_kernel<<<dim3(16,64), blk, 0, stream>>>(obuf, Wo, (float*)d_out, BN_, D_, D_);
}

// Round 4
// 1722.543 us; speedup vs baseline: 1.9642x; 1.6130x over previous
//
#include <hip/hip_runtime.h>
#include <hip/hip_bf16.h>
#include <math.h>

#define B_ 2
#define N_ 2048
#define D_ 1024
#define H_ 16
#define DH_ 64
#define BN_ (B_*N_)
#define CHUNK_ 64
#define NCHUNK_ (N_/CHUNK_)
#define CG_ITERS_ 30

typedef __attribute__((ext_vector_type(8))) short short8;
typedef __attribute__((ext_vector_type(4))) float floatx4;

// split fp32 -> (hi,lo) bf16 with RNE
__device__ __forceinline__ void split_bf16(float f, unsigned short &hi, unsigned short &lo){
  unsigned u = __float_as_uint(f);
  unsigned r = u + 0x7FFF + ((u>>16)&1);
  hi = (unsigned short)(r>>16);
  float fh = __uint_as_float((unsigned)hi<<16);
  float fl = f - fh;
  unsigned ul = __float_as_uint(fl);
  unsigned rl = ul + 0x7FFF + ((ul>>16)&1);
  lo = (unsigned short)(rl>>16);
}

// ---------------- split-bf16 MFMA GEMM: C = A @ B (fp32 in/out) ----------------
// A row-major [M][K], B row-major [K][N], C [M][N]. M%128==0, N%64==0, K%32==0.
// Tile 128x64, BK=32, 256 threads (4 waves). Wave w owns m-band [w*32,w*32+32).
// Split: C = Ah*Bh + Ah*Bl + Al*Bh (bf16 MFMA, fp32 acc). ~2^-17 rel error.
#define LDSP 40   // padded row stride (bf16 elems): 80B, 16B-aligned, ~2-way banks
__global__ __launch_bounds__(256) void mfma_gemm(const float* __restrict__ A,
    const float* __restrict__ Bm, float* __restrict__ C, int M, int N, int K)
{
  __shared__ short Ahs[128*LDSP];
  __shared__ short Als[128*LDSP];
  __shared__ short Bhs[64*LDSP];
  __shared__ short Bls[64*LDSP];
  const int tid = threadIdx.x;
  const int lane = tid & 63;
  const int wave = tid >> 6;
  const int m0 = blockIdx.y * 128;
  const int n0 = blockIdx.x * 64;

  floatx4 acc[2][4];
#pragma unroll
  for (int mi=0;mi<2;mi++)
#pragma unroll
    for (int ni=0;ni<4;ni++) acc[mi][ni] = (floatx4){0.f,0.f,0.f,0.f};

  const int arow = tid >> 2;           // 0..63 (two iters -> 128 rows)
  const int acol = (tid & 3) * 8;      // 0,8,16,24
  const int bn   = tid & 63;           // 0..63
  const int bkb  = (tid >> 6) * 8;     // 0,8,16,24

  for (int k0=0; k0<K; k0+=32){
    // ---- stage A tile 128x32 (split on the fly) ----
#pragma unroll
    for (int it=0; it<2; it++){
      int row = it*64 + arow;
      const float* src = &A[(size_t)(m0+row)*K + k0 + acol];
      float4 f0 = *(const float4*)(src);
      float4 f1 = *(const float4*)(src+4);
      unsigned short h[8], l[8];
      split_bf16(f0.x,h[0],l[0]); split_bf16(f0.y,h[1],l[1]);
      split_bf16(f0.z,h[2],l[2]); split_bf16(f0.w,h[3],l[3]);
      split_bf16(f1.x,h[4],l[4]); split_bf16(f1.y,h[5],l[5]);
      split_bf16(f1.z,h[6],l[6]); split_bf16(f1.w,h[7],l[7]);
      short8 hv, lv;
#pragma unroll
      for (int j=0;j<8;j++){ hv[j]=(short)h[j]; lv[j]=(short)l[j]; }
      *(short8*)&Ahs[row*LDSP + acol] = hv;
      *(short8*)&Als[row*LDSP + acol] = lv;
    }
    // ---- stage B tile 32x64 transposed -> [n][k] (split on the fly) ----
    {
      unsigned short h[8], l[8];
#pragma unroll
      for (int j=0;j<8;j++){
        float f = Bm[(size_t)(k0+bkb+j)*N + n0 + bn];
        split_bf16(f, h[j], l[j]);
      }
      short8 hv, lv;
#pragma unroll
      for (int j=0;j<8;j++){ hv[j]=(short)h[j]; lv[j]=(short)l[j]; }
      *(short8*)&Bhs[bn*LDSP + bkb] = hv;
      *(short8*)&Bls[bn*LDSP + bkb] = lv;
    }
    __syncthreads();
    // ---- MFMA: frag k-index = (lane>>4)*8, m/n = lane&15 ----
    const int fk = (lane>>4)*8;
    const int fm = lane & 15;
    short8 ah[2], al[2];
#pragma unroll
    for (int mi=0;mi<2;mi++){
      int row = wave*32 + mi*16 + fm;
      ah[mi] = *(const short8*)&Ahs[row*LDSP + fk];
      al[mi] = *(const short8*)&Als[row*LDSP + fk];
    }
#pragma unroll
    for (int ni=0;ni<4;ni++){
      int nrow = ni*16 + fm;
      short8 bh = *(const short8*)&Bhs[nrow*LDSP + fk];
      short8 bl = *(const short8*)&Bls[nrow*LDSP + fk];
#pragma unroll
      for (int mi=0;mi<2;mi++){
        acc[mi][ni] = __builtin_amdgcn_mfma_f32_16x16x32_bf16(ah[mi], bh, acc[mi][ni], 0,0,0);
        acc[mi][ni] = __builtin_amdgcn_mfma_f32_16x16x32_bf16(ah[mi], bl, acc[mi][ni], 0,0,0);
        acc[mi][ni] = __builtin_amdgcn_mfma_f32_16x16x32_bf16(al[mi], bh, acc[mi][ni], 0,0,0);
      }
    }
    __syncthreads();
  }
  // ---- epilogue: C/D layout col=lane&15, row=(lane>>4)*4+reg ----
  const int quad = lane >> 4;
  const int fcol = lane & 15;
#pragma unroll
  for (int mi=0;mi<2;mi++)
#pragma unroll
    for (int ni=0;ni<4;ni++)
#pragma unroll
      for (int rg=0;rg<4;rg++){
        int row = m0 + wave*32 + mi*16 + quad*4 + rg;
        int col = n0 + ni*16 + fcol;
        C[(size_t)row*N + col] = acc[mi][ni][rg];
      }
}

// ---------------- generic tiled GEMM (fp32) for small-N projections ----------------
__global__ __launch_bounds__(256) void gemm_kernel(const float* __restrict__ A,
    const float* __restrict__ Bm, float* __restrict__ C, int M, int N, int K)
{
  __shared__ float As[16][65];
  __shared__ float Bs[16][65];
  const int tid = threadIdx.x;
  const int tile_m = blockIdx.y * 64;
  const int tile_n = blockIdx.x * 64;
  const int tr = tid >> 4;
  const int tc = tid & 15;
  float acc[4][4];
#pragma unroll
  for (int i=0;i<4;i++)
#pragma unroll
    for (int j=0;j<4;j++) acc[i][j]=0.f;

  for (int k0=0;k0<K;k0+=16) {
#pragma unroll
    for (int i=0;i<4;i++){
      int flat = i*256+tid;
      int ar = flat>>4, ak = flat&15;
      As[ak][ar] = A[(size_t)(tile_m+ar)*K + k0+ak];
      int kr = flat>>6, cc = flat&63;
      int col = tile_n + cc;
      Bs[kr][cc] = (col < N) ? Bm[(size_t)(k0+kr)*N + col] : 0.f;
    }
    __syncthreads();
#pragma unroll
    for (int kk=0;kk<16;kk++){
      float a[4], b[4];
#pragma unroll
      for (int u=0;u<4;u++){ a[u]=As[kk][tr*4+u]; b[u]=Bs[kk][tc*4+u]; }
#pragma unroll
      for (int i=0;i<4;i++)
#pragma unroll
        for (int j=0;j<4;j++) acc[i][j] += a[i]*b[j];
    }
    __syncthreads();
  }
#pragma unroll
  for (int i=0;i<4;i++){
#pragma unroll
    for (int j=0;j<4;j++){
      int col = tile_n + tc*4+j;
      if (col < N) C[(size_t)(tile_m + tr*4+i)*N + col] = acc[i][j];
    }
  }
}

// ---------------- lamb = softplus(lamb_params) + 0.25 ----------------
__global__ void k_lamb(const float* __restrict__ lp, float* __restrict__ lamb){
  int i = blockIdx.x*256 + threadIdx.x;
  if (i < D_){
    float z = lp[i];
    float sp = fmaxf(z, 0.f) + log1pf(expf(-fabsf(z)));
    lamb[i] = sp + 0.25f;
  }
}

// ---------------- per-head l2norm of q,k (in place) ----------------
__global__ __launch_bounds__(256) void k_l2norm(float* __restrict__ q, float* __restrict__ k){
  int bn = blockIdx.x;
  int wave = threadIdx.x >> 6, lane = threadIdx.x & 63;
#pragma unroll
  for (int e=0; e<4; e++){
    int h = e*4 + wave;
    size_t idx = (size_t)bn*D_ + h*DH_ + lane;
    float qv = q[idx], kv = k[idx];
    float sq = qv*qv, sk = kv*kv;
#pragma unroll
    for (int off=32; off>=1; off>>=1){ sq += __shfl_xor(sq, off); sk += __shfl_xor(sk, off); }
    q[idx] = qv * rsqrtf(sq + 1e-6f);
    k[idx] = kv * rsqrtf(sk + 1e-6f);
  }
}

// ---------------- log_f, beta, cumulative F per (b,h) ----------------
__global__ __launch_bounds__(256) void k_scan(const float* __restrict__ flogit,
    const float* __restrict__ blogit, const float* __restrict__ delta,
    float* __restrict__ logf, float* __restrict__ F, float* __restrict__ beta)
{
  int bh = blockIdx.x; int b = bh >> 4; int h = bh & 15;
  int tid = threadIdx.x;
  __shared__ float tot[256];
  float dl = delta[h];
  float loc[8];
  float run = 0.f;
#pragma unroll
  for (int u=0;u<8;u++){
    int t = tid*8+u;
    float z = flogit[(size_t)(b*N_+t)*H_ + h] + dl;
    float lf = fminf(z,0.f) - log1pf(expf(-fabsf(z)));
    logf[(size_t)bh*N_ + t] = lf;
    float zb = blogit[(size_t)(b*N_+t)*H_ + h];
    beta[(size_t)bh*N_ + t] = 1.f/(1.f+expf(-zb));
    run += lf; loc[u] = run;
  }
  tot[tid] = run;
  __syncthreads();
  for (int off=1; off<256; off<<=1){
    float add = (tid>=off)? tot[tid-off] : 0.f;
    __syncthreads();
    tot[tid] += add;
    __syncthreads();
  }
  float offset = (tid>0)? tot[tid-1] : 0.f;
#pragma unroll
  for (int u=0;u<8;u++){
    F[(size_t)bh*N_ + tid*8+u] = offset + loc[u];
  }
}

// ---------------- chunk-local weighted Gram sums (at chunk END) ----------------
__global__ __launch_bounds__(256) void k_chunk(const float* __restrict__ kg,
    const float* __restrict__ vg, const float* __restrict__ F,
    const float* __restrict__ beta, float* __restrict__ Skk, float* __restrict__ Skv)
{
  int blk = blockIdx.x;
  int c = blk & (NCHUNK_-1); int bh = blk >> 5; int b = bh >> 4; int h = bh & 15;
  int t0 = c*CHUNK_;
  int tid = threadIdx.x;
  __shared__ float Ks[64][65];
  __shared__ float Vs[64][65];
  __shared__ float w[64];
#pragma unroll 4
  for (int i=0;i<16;i++){
    int flat=i*256+tid; int s=flat>>6; int j=flat&63;
    size_t g = (size_t)(b*N_+t0+s)*D_ + h*DH_ + j;
    Ks[s][j] = kg[g]; Vs[s][j] = vg[g];
  }
  if (tid < 64){
    float Fe = F[(size_t)bh*N_ + t0 + 63];
    w[tid] = expf(Fe - F[(size_t)bh*N_ + t0 + tid]) * beta[(size_t)bh*N_ + t0 + tid];
  }
  __syncthreads();
  int i0 = (tid>>4)<<2, j0 = (tid&15)<<2;
  float akk[4][4], akv[4][4];
#pragma unroll
  for (int a=0;a<4;a++)
#pragma unroll
    for (int bb=0;bb<4;bb++){ akk[a][bb]=0.f; akv[a][bb]=0.f; }
  for (int s=0;s<64;s++){
    float ws_ = w[s];
    float ka[4], kb[4], vb[4];
#pragma unroll
    for (int a=0;a<4;a++){ ka[a] = ws_*Ks[s][i0+a]; kb[a] = Ks[s][j0+a]; vb[a] = Vs[s][j0+a]; }
#pragma unroll
    for (int a=0;a<4;a++)
#pragma unroll
      for (int bb=0;bb<4;bb++){
        akk[a][bb] += ka[a]*kb[bb];
        akv[a][bb] += ka[a]*vb[bb];
      }
  }
  size_t base = ((size_t)bh*NCHUNK_ + c)*4096;
#pragma unroll
  for (int a=0;a<4;a++)
#pragma unroll
    for (int bb=0;bb<4;bb++){
      Skk[base + (size_t)(i0+a)*64 + j0+bb] = akk[a][bb];
      Skv[base + (size_t)(i0+a)*64 + j0+bb] = akv[a][bb];
    }
}

// ---------------- sequential chunk combine: local sums -> chunk-START states ----------------
__global__ __launch_bounds__(256) void k_combine(float* __restrict__ Skk,
    float* __restrict__ Skv, const float* __restrict__ F)
{
  int bh = blockIdx.x; int tid = threadIdx.x;
  float Rkk[16], Rkv[16];
#pragma unroll
  for (int u=0;u<16;u++){ Rkk[u]=0.f; Rkv[u]=0.f; }
  float Fprev = 0.f;
  for (int c=0;c<NCHUNK_;c++){
    float Fe = F[(size_t)bh*N_ + c*CHUNK_ + 63];
    float E = expf(Fe - Fprev);
    Fprev = Fe;
    size_t base = ((size_t)bh*NCHUNK_ + c)*4096;
#pragma unroll
    for (int u=0;u<16;u++){
      size_t e = base + (size_t)u*256 + tid;
      float lkk = Skk[e], lkv = Skv[e];
      Skk[e] = Rkk[u]; Skv[e] = Rkv[u];
      Rkk[u] = E*Rkk[u] + lkk;
      Rkv[u] = E*Rkv[u] + lkv;
    }
  }
}

// ---------------- wave-resident CG solve (S only; writes x_t to xbuf) ----------------
// One wave per (b,h,quarter-chunk of 16 steps). 4096 waves -> 4 waves/SIMD.
__device__ __forceinline__ float wred(float v){
#pragma unroll
  for (int off=32; off>=1; off>>=1) v += __shfl_xor(v, off);
  return v;
}

__global__ __launch_bounds__(64, 4) void k_cgsolve(
    const float* __restrict__ qg, const float* __restrict__ kg,
    const float* __restrict__ logf, const float* __restrict__ beta,
    const float* __restrict__ lamb, const float* __restrict__ Skk,
    float* __restrict__ xbuf)
{
  const int blk = blockIdx.x;           // 4096 = 32 bh * 32 cc * 4 quarters
  const int bh  = blk >> 7;
  const int r   = blk & 127;
  const int cc  = r >> 2;
  const int qd  = r & 3;
  const int b = bh >> 4, h = bh & 15;
  const int lane = threadIdx.x;

  __shared__ __align__(16) float pv[64];
  __shared__ __align__(16) float kv[64];

  float S[64];
  const size_t base = ((size_t)bh*NCHUNK_ + cc)*4096;
  // S symmetric: lane's row == lane's column: coalesced load
#pragma unroll
  for (int j=0;j<64;j++) S[j] = Skk[base + (size_t)j*64 + lane];
  const float laml = lamb[h*DH_ + lane];

  const int tstart  = cc*CHUNK_;
  const int cgstart = tstart + qd*16;

  // ---- replay (state-only) ----
  for (int tt=tstart; tt<cgstart; tt++){
    float fexp = expf(logf[(size_t)bh*N_ + tt]);
    float bet  = beta[(size_t)bh*N_ + tt];
    size_t gidx = (size_t)(b*N_+tt)*D_ + h*DH_ + lane;
    float kl = kg[gidx];
    kv[lane] = kl;
    __syncthreads();
    float bk = bet*kl;
#pragma unroll
    for (int u=0;u<16;u++){
      float4 k4 = *(const float4*)&kv[4*u];
      S[4*u+0] = fexp*S[4*u+0] + bk*k4.x;
      S[4*u+1] = fexp*S[4*u+1] + bk*k4.y;
      S[4*u+2] = fexp*S[4*u+2] + bk*k4.z;
      S[4*u+3] = fexp*S[4*u+3] + bk*k4.w;
    }
    __syncthreads();
  }

  // ---- CG phase: 16 timesteps ----
  for (int tt=cgstart; tt<cgstart+16; tt++){
    float fexp = expf(logf[(size_t)bh*N_ + tt]);
    float bet  = beta[(size_t)bh*N_ + tt];
    size_t gidx = (size_t)(b*N_+tt)*D_ + h*DH_ + lane;
    float kl = kg[gidx], ql = qg[gidx];
    kv[lane] = kl; pv[lane] = ql;
    __syncthreads();
    float bk = bet*kl;
#pragma unroll
    for (int u=0;u<16;u++){
      float4 k4 = *(const float4*)&kv[4*u];
      S[4*u+0] = fexp*S[4*u+0] + bk*k4.x;
      S[4*u+1] = fexp*S[4*u+1] + bk*k4.y;
      S[4*u+2] = fexp*S[4*u+2] + bk*k4.z;
      S[4*u+3] = fexp*S[4*u+3] + bk*k4.w;
    }
    float p_l = ql, r_l = ql, x_l = 0.f;
    float rs = wred(ql*ql);
#pragma unroll 1
    for (int it=0; it<CG_ITERS_; it++){
      float a0=0.f, a1=0.f, a2=0.f, a3=0.f;
#pragma unroll
      for (int u=0;u<16;u++){
        float4 p4 = *(const float4*)&pv[4*u];
        a0 += S[4*u+0]*p4.x;
        a1 += S[4*u+1]*p4.y;
        a2 += S[4*u+2]*p4.z;
        a3 += S[4*u+3]*p4.w;
      }
      float ap = (a0+a1)+(a2+a3) + laml*p_l;
      float pAp = wred(p_l*ap);
      float alpha = rs / (pAp + 1e-12f);
      x_l += alpha * p_l;
      r_l -= alpha * ap;
      float rn = wred(r_l*r_l);
      p_l = r_l + (rn/(rs+1e-12f)) * p_l;
      rs = rn;
      __syncthreads();
      pv[lane] = p_l;
      __syncthreads();
    }
    xbuf[gidx] = x_l;
    __syncthreads();
  }
}

// ---------------- batched output: O = diag(ef)*(X @ Z0) + (W o (X @ K^T)) @ V ----------------
// Per (b,h,chunk). In-place over xbuf (X staged to LDS first).
__global__ __launch_bounds__(256) void k_output(
    const float* __restrict__ kg, const float* __restrict__ vg,
    const float* __restrict__ F, const float* __restrict__ beta,
    const float* __restrict__ Skv, float* __restrict__ xo)
{
  int blk = blockIdx.x;
  int c = blk & (NCHUNK_-1); int bh = blk >> 5; int bat = bh >> 4; int h = bh & 15;
  int t0 = c*CHUNK_;
  int tid = threadIdx.x;
  __shared__ float Xs[64][68];
  __shared__ float Ks[64][68];
  __shared__ float Vs[64][68];
  __shared__ float Gw[64][68];
  __shared__ float ef[64], ib[64];
#pragma unroll 4
  for (int i=0;i<16;i++){
    int flat=i*256+tid; int rr=flat>>6; int cc2=flat&63;
    size_t g = (size_t)(bat*N_+t0+rr)*D_ + h*DH_ + cc2;
    Xs[rr][cc2] = xo[g]; Ks[rr][cc2] = kg[g]; Vs[rr][cc2] = vg[g];
  }
  if (tid < 64){
    float Fprev = (t0 > 0) ? F[(size_t)bh*N_ + t0 - 1] : 0.f;
    float e = expf(F[(size_t)bh*N_ + t0 + tid] - Fprev);   // chunk-local decay incl. own step
    ef[tid] = e;
    ib[tid] = beta[(size_t)bh*N_ + t0 + tid] / e;
  }
  __syncthreads();
  const int ti = (tid>>4)<<2;    // t-tile base
  const int j0 = (tid&15)<<2;    // s/j-tile base
  // pass 1: Gw[t][s] = (s<=t) ? ef[t]*ib[s] * (x_t . k_s) : 0
  float g4[4][4];
#pragma unroll
  for (int a=0;a<4;a++)
#pragma unroll
    for (int bb=0;bb<4;bb++) g4[a][bb]=0.f;
  for (int i=0;i<64;i++){
    float xa[4], kb[4];
#pragma unroll
    for (int a=0;a<4;a++){ xa[a]=Xs[ti+a][i]; kb[a]=Ks[j0+a][i]; }
#pragma unroll
    for (int a=0;a<4;a++)
#pragma unroll
      for (int bb=0;bb<4;bb++) g4[a][bb] += xa[a]*kb[bb];
  }
#pragma unroll
  for (int a=0;a<4;a++)
#pragma unroll
    for (int bb=0;bb<4;bb++){
      int t = ti+a, s = j0+bb;
      Gw[t][s] = (s <= t) ? g4[a][bb]*ef[t]*ib[s] : 0.f;
    }
  __syncthreads();
  // pass 2: O[t][j] = ef[t]*(X @ Z0)[t][j] + (Gw @ V)[t][j]
  float o4[4][4];
#pragma unroll
  for (int a=0;a<4;a++)
#pragma unroll
    for (int bb=0;bb<4;bb++) o4[a][bb]=0.f;
  const float* Z0 = &Skv[((size_t)bh*NCHUNK_ + c)*4096];
  for (int i=0;i<64;i++){
    float xa[4];
#pragma unroll
    for (int a=0;a<4;a++) xa[a]=Xs[ti+a][i];
    float4 z = *(const float4*)&Z0[(size_t)i*64 + j0];
#pragma unroll
    for (int a=0;a<4;a++){
      o4[a][0] += xa[a]*z.x; o4[a][1] += xa[a]*z.y;
      o4[a][2] += xa[a]*z.z; o4[a][3] += xa[a]*z.w;
    }
  }
#pragma unroll
  for (int a=0;a<4;a++){
    float e = ef[ti+a];
#pragma unroll
    for (int bb=0;bb<4;bb++) o4[a][bb] *= e;
  }
  for (int s=0;s<64;s++){
    float ga[4], vb[4];
#pragma unroll
    for (int a=0;a<4;a++){ ga[a]=Gw[ti+a][s]; vb[a]=Vs[s][j0+a]; }
#pragma unroll
    for (int a=0;a<4;a++)
#pragma unroll
      for (int bb=0;bb<4;bb++) o4[a][bb] += ga[a]*vb[bb];
  }
#pragma unroll
  for (int a=0;a<4;a++)
#pragma unroll
    for (int bb=0;bb<4;bb++){
      xo[(size_t)(bat*N_+t0+ti+a)*D_ + h*DH_ + j0+bb] = o4[a][bb];
    }
}

// ---------------- gate + grouped RMSNorm (in place on o) ----------------
__global__ __launch_bounds__(256) void k_gate(float* __restrict__ o,
    const float* __restrict__ g1, const float* __restrict__ gw2,
    const float* __restrict__ nw)
{
  int bn = blockIdx.x;
  int tid = threadIdx.x;
  __shared__ float g1s[64];
  if (tid < 64) g1s[tid] = g1[(size_t)bn*DH_ + tid];
  __syncthreads();
  int wave = tid>>6, lane = tid&63;
#pragma unroll
  for (int e=0;e<4;e++){
    int h = e*4 + wave;
    int col = h*DH_ + lane;
    float zl = 0.f;
    for (int cc=0; cc<64; cc++){
      zl += g1s[cc] * gw2[(size_t)cc*D_ + col];
    }
    float gate = 1.f/(1.f+expf(-zl));
    size_t idx = (size_t)bn*D_ + col;
    float og = o[idx] * gate;
    float ss = og*og;
#pragma unroll
    for (int off=32; off>=1; off>>=1) ss += __shfl_xor(ss, off);
    og *= rsqrtf(ss*(1.f/64.f) + 1e-5f);
    og *= nw[col];
    o[idx] = og;
  }
}

// ---------------- workspace layout (floats) ----------------
#define OFF_Q      ((size_t)0)
#define OFF_K      ((size_t)4194304)
#define OFF_V      ((size_t)8388608)
#define OFF_O      ((size_t)12582912)
#define OFF_SKK    ((size_t)16777216)
#define OFF_SKV    ((size_t)20971520)
#define OFF_G1     ((size_t)25165824)
#define OFF_FLOG   ((size_t)25427968)
#define OFF_BLOG   ((size_t)25493504)
#define OFF_LOGF   ((size_t)25559040)
#define OFF_F      ((size_t)25624576)
#define OFF_BETA   ((size_t)25690112)
#define OFF_LAMB   ((size_t)25755648)
// total 25,756,672 floats = 103.0 MB

extern "C" void kernel_launch(void* const* d_in, const int* in_sizes, int n_in,
                              void* d_out, int out_size, void* d_ws, size_t ws_size,
                              hipStream_t stream)
{
  const float* x     = (const float*)d_in[0];
  const float* Wq    = (const float*)d_in[1];
  const float* Wk    = (const float*)d_in[2];
  const float* Wv    = (const float*)d_in[3];
  const float* Wf    = (const float*)d_in[4];
  const float* Wbet  = (const float*)d_in[5];
  const float* Wo    = (const float*)d_in[6];
  const float* delta = (const float*)d_in[7];
  const float* lambp = (const float*)d_in[8];
  const float* nw    = (const float*)d_in[9];
  const float* gw1   = (const float*)d_in[10];
  const float* gw2   = (const float*)d_in[11];

  float* ws = (float*)d_ws;
  float* q      = ws + OFF_Q;
  float* kbuf   = ws + OFF_K;
  float* vbuf   = ws + OFF_V;
  float* obuf   = ws + OFF_O;
  float* Skk    = ws + OFF_SKK;
  float* Skv    = ws + OFF_SKV;
  float* g1     = ws + OFF_G1;
  float* flogit = ws + OFF_FLOG;
  float* blogit = ws + OFF_BLOG;
  float* logf   = ws + OFF_LOGF;
  float* F      = ws + OFF_F;
  float* beta   = ws + OFF_BETA;
  float* lamb   = ws + OFF_LAMB;

  dim3 blk(256,1,1);
  // big projections: split-bf16 MFMA GEMM (4096x1024x1024)
  mfma_gemm<<<dim3(16,32), blk, 0, stream>>>(x, Wq, q,    BN_, D_, D_);
  mfma_gemm<<<dim3(16,32), blk, 0, stream>>>(x, Wk, kbuf, BN_, D_, D_);
  mfma_gemm<<<dim3(16,32), blk, 0, stream>>>(x, Wv, vbuf, BN_, D_, D_);
  // small projections: fp32
  gemm_kernel<<<dim3(1,64),  blk, 0, stream>>>(x, Wf,   flogit, BN_, H_,  D_);
  gemm_kernel<<<dim3(1,64),  blk, 0, stream>>>(x, Wbet, blogit, BN_, H_,  D_);
  gemm_kernel<<<dim3(1,64),  blk, 0, stream>>>(x, gw1,  g1,     BN_, DH_, D_);
  // small prep
  k_lamb<<<dim3(4), blk, 0, stream>>>(lambp, lamb);
  k_l2norm<<<dim3(BN_), blk, 0, stream>>>(q, kbuf);
  k_scan<<<dim3(B_*H_), blk, 0, stream>>>(flogit, blogit, delta, logf, F, beta);
  // chunked linear scan of Gram states
  k_chunk<<<dim3(B_*H_*NCHUNK_), blk, 0, stream>>>(kbuf, vbuf, F, beta, Skk, Skv);
  k_combine<<<dim3(B_*H_), blk, 0, stream>>>(Skk, Skv, F);
  // CG solves (writes x_t into obuf region)
  k_cgsolve<<<dim3(B_*H_*NCHUNK_*4), dim3(64,1,1), 0, stream>>>(
      q, kbuf, logf, beta, lamb, Skk, obuf);
  // batched output contraction (in-place on obuf)
  k_output<<<dim3(B_*H_*NCHUNK_), blk, 0, stream>>>(kbuf, vbuf, F, beta, Skv, obuf);
  // epilogue: gate + grouped RMSNorm, then output projection (MFMA)
  k_gate<<<dim3(BN_), blk, 0, stream>>>(obuf, g1, gw2, nw);
  mfma_gemm<<<dim3(16,32), blk, 0, stream>>>(obuf, Wo, (float*)d_out, BN_, D_, D_);
}